// Round 9
// baseline (422.595 us; speedup 1.0000x reference)
//
#include <hip/hip_runtime.h>

// ---------------------------------------------------------------------------
// CausalPD backbone: QKV proj -> fused causal attn + bilinear-bias + L2 norms
// -> out proj.  B=8, L=1024, D=1024, H=16, DK=64.
// R9: dense bias path factored out of the attn k-loop:
//     M = C^T V, G = C^T C per (b,h) (k_mg, 64x64 each);
//     attn loop runs causal-valid tiles only (avg 17/32), computing
//     S, PV, and EC = sum_k e*c (for Cc) via MFMA; epilogue does
//     acc2 = cb@M, B2 = cb^T G cb, Cc = EC.cb with shuffle redistribution.
// ---------------------------------------------------------------------------

typedef __bf16 bf16;
typedef __bf16 bf16x8 __attribute__((ext_vector_type(8)));
typedef __bf16 bf16x4 __attribute__((ext_vector_type(4)));
typedef float  f32x4  __attribute__((ext_vector_type(4)));

#define DEV static __device__ __forceinline__

DEV f32x4 mfma16(bf16x8 a, bf16x8 b, f32x4 c) {
  return __builtin_amdgcn_mfma_f32_16x16x32_bf16(a, b, c, 0, 0, 0);
}

// async global->LDS, 16B per lane (dest = wave-uniform base + lane*16).
DEV void async16(void* lds, const void* g) {
  auto* d = reinterpret_cast<__attribute__((address_space(3))) unsigned int*>(
      (unsigned long long)lds);
  auto* s = reinterpret_cast<const __attribute__((address_space(1))) unsigned int*>(
      (unsigned long long)g);
  __builtin_amdgcn_global_load_lds(s, d, 16, 0, 0);
}

// --------------------------- prep kernels ----------------------------------

__global__ __launch_bounds__(256) void k_cvt(const float* __restrict__ in,
                                             bf16* __restrict__ out, int n4) {
  int i = blockIdx.x * 256 + threadIdx.x;
  if (i >= n4) return;
  f32x4 v = ((const f32x4*)in)[i];
  bf16x4 o = {(bf16)v.x, (bf16)v.y, (bf16)v.z, (bf16)v.w};
  ((bf16x4*)out)[i] = o;
}

// W [1024 k][1024 n] f32  ->  Wt [1024 n][1024 k] bf16
__global__ __launch_bounds__(256) void k_transpose_w(const float* __restrict__ in,
                                                     bf16* __restrict__ out) {
  __shared__ float t[64][65];
  const int k0 = blockIdx.x * 64, n0 = blockIdx.y * 64;
  for (int e = threadIdx.x; e < 4096; e += 256) {
    int r = e >> 6, c = e & 63;
    t[r][c] = in[(size_t)(k0 + r) * 1024 + n0 + c];
  }
  __syncthreads();
  for (int e = threadIdx.x; e < 4096; e += 256) {
    int r = e >> 6, c = e & 63;
    out[(size_t)(n0 + r) * 1024 + k0 + c] = (bf16)t[c][r];
  }
}

// c [bh][1024 k][64 e] -> cT [bh][64 e][1024 k]   (bf16)
__global__ __launch_bounds__(256) void k_transpose_c(const bf16* __restrict__ in,
                                                     bf16* __restrict__ out) {
  __shared__ bf16 t[64][65];
  const int bh = blockIdx.y, k0 = blockIdx.x * 64;
  const bf16* src = in + (size_t)bh * 65536;
  bf16* dst = out + (size_t)bh * 65536;
  for (int e = threadIdx.x; e < 4096; e += 256) {
    int r = e >> 6, c = e & 63;
    t[r][c] = src[(size_t)(k0 + r) * 64 + c];
  }
  __syncthreads();
  for (int e = threadIdx.x; e < 4096; e += 256) {
    int r = e >> 6, c = e & 63;             // r = e, c = k offset
    dst[(size_t)r * 1024 + k0 + c] = t[c][r];
  }
}

// per (b,l,h): LayerNorm over 64 dims, then cb = c @ bilinear.
// bil kept register-resident per wave (verified R8: coalesced, ~25 us).
__global__ __launch_bounds__(256, 4) void k_ln_bilinear(
    const float* __restrict__ ctx, const float* __restrict__ bil,
    const float* __restrict__ gam, const float* __restrict__ bet,
    bf16* __restrict__ c_out, bf16* __restrict__ cb_out) {
  const int w = threadIdx.x >> 6, lane = threadIdx.x & 63;
  float bilreg[64];
#pragma unroll
  for (int e = 0; e < 64; ++e) bilreg[e] = bil[e * 64 + lane];
  const float gm = gam[lane], bt = bet[lane];
  const int wid = blockIdx.x * 4 + w;          // [0, 8192)
  for (int it = 0; it < 16; ++it) {
    const int row = wid * 16 + it;             // = bl*16 + h
    const int h = row & 15, bl = row >> 4;
    const float x = ctx[(size_t)row * 64 + lane];
    float s1 = x, s2 = x * x;
#pragma unroll
    for (int mm = 32; mm >= 1; mm >>= 1) {
      s1 += __shfl_xor(s1, mm);
      s2 += __shfl_xor(s2, mm);
    }
    const float mu = s1 * 0.015625f;
    const float var = s2 * 0.015625f - mu * mu;
    const float cv = (x - mu) * rsqrtf(var + 1e-5f) * gm + bt;
    float a0 = 0.f, a1 = 0.f, a2 = 0.f, a3 = 0.f;
#pragma unroll
    for (int e = 0; e < 64; e += 4) {
      a0 += __int_as_float(__builtin_amdgcn_readlane(__float_as_int(cv), e + 0)) * bilreg[e + 0];
      a1 += __int_as_float(__builtin_amdgcn_readlane(__float_as_int(cv), e + 1)) * bilreg[e + 1];
      a2 += __int_as_float(__builtin_amdgcn_readlane(__float_as_int(cv), e + 2)) * bilreg[e + 2];
      a3 += __int_as_float(__builtin_amdgcn_readlane(__float_as_int(cv), e + 3)) * bilreg[e + 3];
    }
    const float acc = (a0 + a1) + (a2 + a3);
    const size_t o =
        ((size_t)((bl >> 10) * 16 + h) * 1024 + (bl & 1023)) * 64 + lane;
    c_out[o] = (bf16)cv;
    cb_out[o] = (bf16)acc;
  }
}

// per (b,h): Mt[d][e] = sum_k vT[d][k] cT[e][k]  (blockIdx.x==0)
//            G [e][f] = sum_k cT[e][k] cT[f][k]  (blockIdx.x==1)
// mg layout: [bh][ Mt 64x64 | G 64x64 ] bf16.
__global__ __launch_bounds__(256) void k_mg(const bf16* __restrict__ vT,
                                            const bf16* __restrict__ cT,
                                            bf16* __restrict__ mg) {
  const int which = blockIdx.x, bh = blockIdx.y;
  const int w = threadIdx.x >> 6, lane = threadIdx.x & 63;
  const int g = lane >> 4, x = lane & 15;
  const bf16* A = (which ? cT : vT) + (size_t)bh * 65536;
  const bf16* Bm = cT + (size_t)bh * 65536;
  f32x4 acc[4];
#pragma unroll
  for (int nt = 0; nt < 4; ++nt) acc[nt] = f32x4{0.f, 0.f, 0.f, 0.f};
  const bf16* arow = A + (size_t)(w * 16 + x) * 1024 + 8 * g;
  for (int k = 0; k < 32; ++k) {
    const bf16x8 af = *(const bf16x8*)(arow + k * 32);
#pragma unroll
    for (int nt = 0; nt < 4; ++nt) {
      const bf16x8 bf = *(const bf16x8*)(Bm + (size_t)(nt * 16 + x) * 1024 +
                                         k * 32 + 8 * g);
      acc[nt] = mfma16(af, bf, acc[nt]);
    }
  }
  bf16* out = mg + (size_t)bh * 8192 + which * 4096;
#pragma unroll
  for (int nt = 0; nt < 4; ++nt)
#pragma unroll
    for (int j = 0; j < 4; ++j)
      out[(w * 16 + 4 * g + j) * 64 + nt * 16 + x] = (bf16)acc[nt][j];
}

// --------------------------- GEMM (128x128x32) -----------------------------
// z<2: out bf16 scattered to [B,H,L,DK]; z==2: out bf16 to vT [B,H,DK,L];
// mode==3: out f32 [8192,1024].

struct GemmPtrs {
  const bf16* Bt[3];
  bf16* ob[3];
  const float* bias[3];
};

__global__ __launch_bounds__(256) void k_gemm(const bf16* __restrict__ A,
                                              GemmPtrs p,
                                              float* __restrict__ outf,
                                              int mode) {
  __shared__ __align__(16) bf16 lds[2][2][4096];   // [buf][A/B][128*32]
  const int tid = threadIdx.x;
  const int bm = blockIdx.x, bn = blockIdx.y, z = blockIdx.z;
  const int w = tid >> 6, lane = tid & 63, g = lane >> 4, x = lane & 15;
  const int wr = w >> 1, wc = w & 1;
  const bf16* Bt = p.Bt[z];
  const float* bias = p.bias[z];
  bf16* ob = p.ob[z];

  f32x4 acc[4][4];
#pragma unroll
  for (int mt = 0; mt < 4; ++mt)
#pragma unroll
    for (int nt = 0; nt < 4; ++nt) acc[mt][nt] = f32x4{0.f, 0.f, 0.f, 0.f};

  const bf16* Ab = A + (size_t)bm * 128 * 1024;
  const bf16* Bb = Bt + (size_t)bn * 128 * 1024;

  auto stage = [&](int buf, int t) {
#pragma unroll
    for (int i = 0; i < 2; ++i) {
      int ch = i * 256 + tid;
      int r = ch >> 2, s = ch & 3;
      int sg = (s ^ ((r >> 1) & 3)) * 8;
      async16(&lds[buf][0][ch * 8], Ab + (size_t)r * 1024 + t * 32 + sg);
      async16(&lds[buf][1][ch * 8], Bb + (size_t)r * 1024 + t * 32 + sg);
    }
  };

  stage(0, 0);
  const int sa = (g ^ ((x >> 1) & 3)) * 8;   // swizzled slot for reads
  for (int kt = 0; kt < 32; ++kt) {
    __syncthreads();
    if (kt + 1 < 32) stage((kt + 1) & 1, kt + 1);
    const bf16* la = lds[kt & 1][0];
    const bf16* lb = lds[kt & 1][1];
    bf16x8 af[4], bfr[4];
#pragma unroll
    for (int mt = 0; mt < 4; ++mt)
      af[mt] = *(const bf16x8*)(la + (wr * 64 + mt * 16 + x) * 32 + sa);
#pragma unroll
    for (int nt = 0; nt < 4; ++nt)
      bfr[nt] = *(const bf16x8*)(lb + (wc * 64 + nt * 16 + x) * 32 + sa);
#pragma unroll
    for (int mt = 0; mt < 4; ++mt)
#pragma unroll
      for (int nt = 0; nt < 4; ++nt)
        acc[mt][nt] = mfma16(af[mt], bfr[nt], acc[mt][nt]);
  }

  const int ibase = bm * 128 + wr * 64;
  const int jbase = bn * 128 + wc * 64;
  float bias4[4];
#pragma unroll
  for (int nt = 0; nt < 4; ++nt) bias4[nt] = bias[jbase + nt * 16 + x];

  if (mode < 3) {
    if (z == 2) {
      // V: write transposed [bh][dk][l]; 4 consecutive l -> bf16x4 store.
#pragma unroll
      for (int mt = 0; mt < 4; ++mt)
#pragma unroll
        for (int nt = 0; nt < 4; ++nt) {
          const int jj = jbase + nt * 16 + x;
          const int hh = jj >> 6, dk = jj & 63;
          const int i0 = ibase + mt * 16 + 4 * g;
          const int bb = i0 >> 10, l0 = i0 & 1023;
          bf16x4 v4 = {(bf16)(acc[mt][nt][0] + bias4[nt]),
                       (bf16)(acc[mt][nt][1] + bias4[nt]),
                       (bf16)(acc[mt][nt][2] + bias4[nt]),
                       (bf16)(acc[mt][nt][3] + bias4[nt])};
          *(bf16x4*)&ob[((size_t)(bb * 16 + hh) * 64 + dk) * 1024 + l0] = v4;
        }
    } else {
#pragma unroll
      for (int mt = 0; mt < 4; ++mt)
#pragma unroll
        for (int nt = 0; nt < 4; ++nt) {
          const int jj = jbase + nt * 16 + x;
          const int hh = jj >> 6, dk = jj & 63;
#pragma unroll
          for (int j = 0; j < 4; ++j) {
            const int i = ibase + mt * 16 + 4 * g + j;
            const int bb = i >> 10, l = i & 1023;
            ob[(((size_t)bb * 16 + hh) * 1024 + l) * 64 + dk] =
                (bf16)(acc[mt][nt][j] + bias4[nt]);
          }
        }
    }
  } else {
#pragma unroll
    for (int mt = 0; mt < 4; ++mt)
#pragma unroll
      for (int nt = 0; nt < 4; ++nt) {
        const int jj = jbase + nt * 16 + x;
#pragma unroll
        for (int j = 0; j < 4; ++j) {
          const int i = ibase + mt * 16 + 4 * g + j;
          outf[(size_t)i * 1024 + jj] = acc[mt][nt][j] + bias4[nt];
        }
      }
  }
}

// --------------------------- fused attention -------------------------------
// Per block: one (b,h), 64 q rows (16 per wave).  Loop over causal-valid
// 32-k tiles ONLY (nK = 2qt+2).  Per tile: S = QK^T, fixed-shift exp,
// PV (acc1 += e*v), EC (acc3 += e*c).  Dense bias handled in epilogue via
// precomputed M (acc2 = cb@M), G (B2 = cb^T G cb); Cc = EC.cb.
__global__ __launch_bounds__(256, 4) void k_attn(
    const bf16* __restrict__ qg, const bf16* __restrict__ kg,
    const bf16* __restrict__ vTg, const bf16* __restrict__ cTg,
    const bf16* __restrict__ cbg, const bf16* __restrict__ mg,
    bf16* __restrict__ ao,
    const float* __restrict__ scale_p, const float* __restrict__ bsp) {
  __shared__ __align__(16) bf16 kl[2][2048];     // [k 32][d 64] 8-slot swizzle
  __shared__ __align__(16) bf16 ctl[2][64][36];  // [e 64][k 32 pad4] chunk swz
  __shared__ __align__(16) bf16 vl[2][64][36];   // [d 64][k 32 pad4] chunk swz
  __shared__ __align__(16) bf16 pe[4][640];      // per-wave [16 q][40]

  const float scl = scale_p[0];
  const float bsc = bsp[0];
  const int tid = threadIdx.x, w = tid >> 6, lane = tid & 63;
  const int g = lane >> 4, x = lane & 15;
  // XCD swizzle: id&7 ~ XCD; per XCD 16 consecutive heads, 16 qtiles inner.
  const int id = blockIdx.x;
  const int xcd = id & 7, sid = id >> 3;
  const int bh = xcd * 16 + (sid >> 4);
  const int qt = sid & 15;
  const int qrow0 = qt * 64 + w * 16;

  const bf16* qrow = qg + ((size_t)bh * 1024 + qrow0 + x) * 64;
  const bf16* cbrow = cbg + ((size_t)bh * 1024 + qrow0 + x) * 64;
  const bf16x8 qf0 = *(const bf16x8*)(qrow + 8 * g);
  const bf16x8 qf1 = *(const bf16x8*)(qrow + 32 + 8 * g);
  const bf16x8 cbf0 = *(const bf16x8*)(cbrow + 8 * g);
  const bf16x8 cbf1 = *(const bf16x8*)(cbrow + 32 + 8 * g);

  f32x4 acc1[4], acc3[4];
#pragma unroll
  for (int i = 0; i < 4; ++i) {
    acc1[i] = f32x4{0.f, 0.f, 0.f, 0.f};
    acc3[i] = f32x4{0.f, 0.f, 0.f, 0.f};
  }
  float Zs = 0.f, E2 = 0.f;

  const bf16* kbh = kg + (size_t)bh * 65536;
  const bf16* ctbh = cTg + (size_t)bh * 65536;
  const bf16* vbh = vTg + (size_t)bh * 65536;
  const int nK = 2 * qt + 2;     // causal-valid 32-row k-tiles

  auto stageK = [&](int buf, int t) {
    const int r = tid >> 3, s = tid & 7;
    const int sg = (s ^ (r & 7)) * 8;
    async16(&kl[buf][tid * 8], kbh + (size_t)(t * 32 + r) * 64 + sg);
  };
  bf16x8 vreg, creg;
  auto loadCV = [&](int t) {
    const int r = tid >> 2, s = tid & 3;
    vreg = *(const bf16x8*)(vbh + (size_t)r * 1024 + t * 32 + s * 8);
    creg = *(const bf16x8*)(ctbh + (size_t)r * 1024 + t * 32 + s * 8);
  };
  auto writeCV = [&](int buf) {
    const int r = tid >> 2, s = tid & 3;
    *(bf16x8*)&vl[buf][r][(s ^ (r & 3)) * 8] = vreg;
    *(bf16x8*)&ctl[buf][r][(s ^ (r & 3)) * 8] = creg;
  };

  stageK(0, 0);
  loadCV(0);
  writeCV(0);
  for (int t = 0; t < nK; ++t) {
    __syncthreads();
    if (t + 1 < nK) {
      stageK((t + 1) & 1, t + 1);
      loadCV(t + 1);
    }
    const bf16* klb = kl[t & 1];
    const int tileK = t * 32;
    const bool hv = tileK <= qrow0 + 15;
    if (hv) {
      float sv[8];
#pragma unroll
      for (int sub = 0; sub < 2; ++sub) {
        const int rloc = sub * 16 + x;
        const int so0 = (g ^ (rloc & 7)) * 8;
        const int so1 = ((4 + g) ^ (rloc & 7)) * 8;
        const int k16 = tileK + sub * 16;
        const bool av = k16 <= qrow0 + 15;
        const bool full = (k16 + 15) <= qrow0;
        f32x4 sacc = f32x4{0.f, 0.f, 0.f, 0.f};
        if (av) {
          const bf16* kr = klb + rloc * 64;
          sacc = mfma16(*(const bf16x8*)(kr + so0), qf0, sacc);
          sacc = mfma16(*(const bf16x8*)(kr + so1), qf1, sacc);
        }
        const int q = qrow0 + x;
#pragma unroll
        for (int j = 0; j < 4; ++j) {
          const int kk = k16 + 4 * g + j;
          sv[sub * 4 + j] =
              full ? sacc[j] * scl
                   : ((av && kk <= q) ? sacc[j] * scl : -1e30f);
        }
      }
      float ev[8];
#pragma unroll
      for (int jj = 0; jj < 8; ++jj) {
        const float e = __expf(sv[jj]);   // exp(-1e30) flushes to 0
        ev[jj] = e;
        Zs += e; E2 += e * e;
      }
      bf16x4 e0 = {(bf16)ev[0], (bf16)ev[1], (bf16)ev[2], (bf16)ev[3]};
      bf16x4 e1 = {(bf16)ev[4], (bf16)ev[5], (bf16)ev[6], (bf16)ev[7]};
      *(bf16x4*)&pe[w][x * 40 + 4 * g] = e0;
      *(bf16x4*)&pe[w][x * 40 + 16 + 4 * g] = e1;
      const bf16x8 pef = *(const bf16x8*)&pe[w][x * 40 + 8 * g];
#pragma unroll
      for (int nt = 0; nt < 4; ++nt) {
        const int dr = nt * 16 + x;
        const int ch = (g ^ (dr & 3)) * 8;
        const bf16x8 vf = *(const bf16x8*)&vl[t & 1][dr][ch];
        const bf16x8 cf = *(const bf16x8*)&ctl[t & 1][dr][ch];
        acc1[nt] = mfma16(pef, vf, acc1[nt]);
        acc3[nt] = mfma16(pef, cf, acc3[nt]);
      }
    }
    if (t + 1 < nK) writeCV((t + 1) & 1);
  }

  // reduce softmax scalars across the 4 lane-groups (per-lane q = qrow0+x)
  Zs += __shfl_xor(Zs, 16); Zs += __shfl_xor(Zs, 32);
  E2 += __shfl_xor(E2, 16); E2 += __shfl_xor(E2, 32);

  // ---- epilogue: cb in row-layout (q = 4g+j, col = nt*16+x) ----
  float cbv[4][4];
#pragma unroll
  for (int nt = 0; nt < 4; ++nt)
#pragma unroll
    for (int j = 0; j < 4; ++j)
      cbv[nt][j] = (float)cbg[((size_t)bh * 1024 + qrow0 + 4 * g + j) * 64 +
                              nt * 16 + x];

  // Cc[q] = EC[q] . cb[q]   (row layout, then x-reduce)
  float cc4[4] = {0.f, 0.f, 0.f, 0.f};
#pragma unroll
  for (int nt = 0; nt < 4; ++nt)
#pragma unroll
    for (int j = 0; j < 4; ++j) cc4[j] += acc3[nt][j] * cbv[nt][j];
#pragma unroll
  for (int j = 0; j < 4; ++j) {
    cc4[j] += __shfl_xor(cc4[j], 1);
    cc4[j] += __shfl_xor(cc4[j], 2);
    cc4[j] += __shfl_xor(cc4[j], 4);
    cc4[j] += __shfl_xor(cc4[j], 8);
  }
  // B2[q] = cb[q]^T G cb[q]:  u = cb@G, then dot with cb (row layout)
  const bf16* Gm = mg + (size_t)bh * 8192 + 4096;
  float b24[4] = {0.f, 0.f, 0.f, 0.f};
#pragma unroll
  for (int nt = 0; nt < 4; ++nt) {
    const bf16* grow = Gm + (nt * 16 + x) * 64;
    f32x4 uu = f32x4{0.f, 0.f, 0.f, 0.f};
    uu = mfma16(cbf0, *(const bf16x8*)(grow + 8 * g), uu);
    uu = mfma16(cbf1, *(const bf16x8*)(grow + 32 + 8 * g), uu);
#pragma unroll
    for (int j = 0; j < 4; ++j) b24[j] += uu[j] * cbv[nt][j];
  }
#pragma unroll
  for (int j = 0; j < 4; ++j) {
    b24[j] += __shfl_xor(b24[j], 1);
    b24[j] += __shfl_xor(b24[j], 2);
    b24[j] += __shfl_xor(b24[j], 4);
    b24[j] += __shfl_xor(b24[j], 8);
  }
  // redistribute row-layout scalars to the lane owning q = x:
  // source lane = 16*(x>>2) + (x&3); its (lane&3)-selected register = q's value
  const int jsel = lane & 3;
  const float ccsel = jsel == 0 ? cc4[0] : jsel == 1 ? cc4[1]
                     : jsel == 2 ? cc4[2] : cc4[3];
  const float b2sel = jsel == 0 ? b24[0] : jsel == 1 ? b24[1]
                     : jsel == 2 ? b24[2] : b24[3];
  const int src = ((x >> 2) << 4) | (x & 3);
  const float CcX = __shfl(ccsel, src);
  const float B2X = fmaxf(__shfl(b2sel, src), 0.f);

  // acc2 = cb @ M  (same layout as acc1: row = q(4g+j), col = d(x))
  const bf16* Mm = mg + (size_t)bh * 8192;
  f32x4 a2[4];
#pragma unroll
  for (int nt = 0; nt < 4; ++nt) {
    const bf16* mrow = Mm + (nt * 16 + x) * 64;
    a2[nt] = f32x4{0.f, 0.f, 0.f, 0.f};
    a2[nt] = mfma16(cbf0, *(const bf16x8*)(mrow + 8 * g), a2[nt]);
    a2[nt] = mfma16(cbf1, *(const bf16x8*)(mrow + 32 + 8 * g), a2[nt]);
  }

  // final coefficients per lane (q = qrow0 + x)
  const float bnorm = fmaxf(sqrtf(B2X), 1e-12f);
  const float invZ = 1.0f / Zs;
  const float n2 = E2 * invZ * invZ + 2.0f * bsc * CcX * invZ / bnorm +
                   bsc * bsc;
  const float inv_an = 1.0f / fmaxf(sqrtf(n2), 1e-12f);
  const float cA = invZ * inv_an;
  const float cB = bsc / bnorm * inv_an;
  const int b_ = bh >> 4, h_ = bh & 15;
#pragma unroll
  for (int j = 0; j < 4; ++j) {
    const int srcq = (lane & 48) | (4 * g + j);
    const float cAj = __shfl(cA, srcq);
    const float cBj = __shfl(cB, srcq);
    const int qr = qrow0 + 4 * g + j;
#pragma unroll
    for (int nt = 0; nt < 4; ++nt) {
      const float o = cAj * acc1[nt][j] + cBj * a2[nt][j];
      ao[(size_t)(b_ * 1024 + qr) * 1024 + h_ * 64 + nt * 16 + x] = (bf16)o;
    }
  }
}

// --------------------------- launcher --------------------------------------

extern "C" void kernel_launch(void* const* d_in, const int* in_sizes, int n_in,
                              void* d_out, int out_size, void* d_ws,
                              size_t ws_size, hipStream_t stream) {
  const float* Q   = (const float*)d_in[0];
  const float* ctx = (const float*)d_in[1];
  // d_in[2] = attn_mask (causal triu) — implemented analytically.
  const float* Wq  = (const float*)d_in[3];
  const float* bq  = (const float*)d_in[4];
  const float* Wk  = (const float*)d_in[5];
  const float* bk  = (const float*)d_in[6];
  const float* Wv  = (const float*)d_in[7];
  const float* bvp = (const float*)d_in[8];
  const float* bil = (const float*)d_in[9];
  const float* gam = (const float*)d_in[10];
  const float* bet = (const float*)d_in[11];
  const float* scl = (const float*)d_in[12];
  const float* bsc = (const float*)d_in[13];
  const float* Wo  = (const float*)d_in[14];
  const float* bo  = (const float*)d_in[15];
  float* out = (float*)d_out;
  char* ws = (char*)d_ws;
  const size_t MB = 1ull << 20;

  bf16* Qb  = (bf16*)(ws + 0);        // 16 MB (reused as ao after QKV GEMM)
  bf16* Wtq = (bf16*)(ws + 16 * MB);  // 2 MB each (dead after QKV GEMM)
  bf16* Wtk = (bf16*)(ws + 18 * MB);
  bf16* Wtv = (bf16*)(ws + 20 * MB);
  bf16* Wto = (bf16*)(ws + 22 * MB);
  bf16* qb  = (bf16*)(ws + 24 * MB);  // 16 MB [B,H,L,DK]
  bf16* kb  = (bf16*)(ws + 40 * MB);
  bf16* cT  = (bf16*)(ws + 56 * MB);  // [B,H,DK(e),L]
  bf16* vT  = (bf16*)(ws + 72 * MB);  // [B,H,DK,L] (written by GEMM z=2)
  bf16* cN  = (bf16*)(ws + 88 * MB);
  bf16* cbN = (bf16*)(ws + 104 * MB);
  bf16* mg  = Wtq;                    // 2 MB alias: Wtq/Wtk dead after GEMM
  bf16* ao  = Qb;                     // alias: Qb dead after QKV GEMM

  k_cvt<<<8192, 256, 0, stream>>>(Q, Qb, 2097152);
  k_transpose_w<<<dim3(16, 16), 256, 0, stream>>>(Wq, Wtq);
  k_transpose_w<<<dim3(16, 16), 256, 0, stream>>>(Wk, Wtk);
  k_transpose_w<<<dim3(16, 16), 256, 0, stream>>>(Wv, Wtv);
  k_transpose_w<<<dim3(16, 16), 256, 0, stream>>>(Wo, Wto);
  k_ln_bilinear<<<2048, 256, 0, stream>>>(ctx, bil, gam, bet, cN, cbN);
  k_transpose_c<<<dim3(16, 128), 256, 0, stream>>>(cN, cT);

  GemmPtrs p1{{Wtq, Wtk, Wtv}, {qb, kb, vT}, {bq, bk, bvp}};
  k_gemm<<<dim3(64, 8, 3), 256, 0, stream>>>(Qb, p1, nullptr, 0);

  k_mg<<<dim3(2, 128), 256, 0, stream>>>(vT, cT, mg);
  k_attn<<<2048, 256, 0, stream>>>(qb, kb, vT, cT, cbN, mg, ao, scl, bsc);

  GemmPtrs p2{{Wto, Wto, Wto}, {nullptr, nullptr, nullptr}, {bo, bo, bo}};
  k_gemm<<<dim3(64, 8, 1), 256, 0, stream>>>(ao, p2, out, 3);

  (void)in_sizes; (void)n_in; (void)out_size; (void)ws_size;
}